// Round 5
// baseline (113.393 us; speedup 1.0000x reference)
//
#include <hip/hip_runtime.h>
#include <hip/hip_bf16.h>

#define NS 64
#define NP 32
#define DIM 128
#define BATCH_N 16384

typedef float f32x4 __attribute__((ext_vector_type(4)));
typedef _Float16 f16x8 __attribute__((ext_vector_type(8)));
typedef unsigned int u32;
typedef unsigned long long u64;

// fp32 -> fp16 (RNE via hardware cvt)
__device__ __forceinline__ unsigned short f2h(float f) {
    _Float16 h = (_Float16)f;
    return __builtin_bit_cast(unsigned short, h);
}

// ---------------------------------------------------------------------------
// prep 1: pair-compressed fp16 MFMA A-operand fragments.
// Pair p combines sites s0=2p, s1=2p+1. Terms (all 128x128, fp32 products):
//   t0 = A0@B0   (always)          t1 = (A1-A0)@B0      (factor b0)
//   t2 = A0@(B1-B0) (factor b1)    t3 = (A1-A0)@(B1-B0) (factor b0*b1)
// Fragment layout (same as before): frag[p][t][kk][mm][lane][j], value =
// T[k][m], k = kk*32 + (lane>>4)*8 + j, m = mm*16 + (lane&15).
// Grid: 128 blocks = (pair 32) x (kk 4); 256 threads = kgrp(8) x mgrp(32),
// thread tile k4 x m4, fp32 MACs in registers, operands LDS-staged.
// ---------------------------------------------------------------------------
__global__ __launch_bounds__(256)
void prep_pair_frags(const float* __restrict__ data,
                     unsigned short* __restrict__ afrag) {
    __shared__ float LA[2 * 32 * 129];   // [L][k_local][j], pad 129
    __shared__ float LB[2 * 32 * 128];   // [R][j_local][m], chunked over j

    const int p   = blockIdx.x >> 2;
    const int kk  = blockIdx.x & 3;
    const int tid = threadIdx.x;
    const int kgrp = tid >> 5;          // 0..7
    const int mgrp = tid & 31;          // 0..31

    const float* A0 = data + ((size_t)(2 * p) * 2 + 0) * DIM * DIM;
    const float* A1 = A0 + DIM * DIM;
    const float* B0 = data + ((size_t)(2 * p + 1) * 2 + 0) * DIM * DIM;
    const float* B1 = B0 + DIM * DIM;

    // stage LA rows k in [kk*32, kk*32+32)
    for (int c = tid; c < 32 * DIM; c += 256) {
        int kl = c >> 7, j = c & 127;
        float a0 = A0[(kk * 32 + kl) * DIM + j];
        float a1 = A1[(kk * 32 + kl) * DIM + j];
        LA[kl * 129 + j] = a0;
        LA[32 * 129 + kl * 129 + j] = a1 - a0;
    }

    float acc[2][2][4][4];
#pragma unroll
    for (int L = 0; L < 2; ++L)
#pragma unroll
        for (int R = 0; R < 2; ++R)
#pragma unroll
            for (int i = 0; i < 4; ++i)
#pragma unroll
                for (int mi = 0; mi < 4; ++mi) acc[L][R][i][mi] = 0.f;

    for (int ch = 0; ch < 4; ++ch) {
        __syncthreads();
        for (int c = tid; c < 32 * DIM; c += 256) {
            int jl = c >> 7, m = c & 127;
            float b0 = B0[(ch * 32 + jl) * DIM + m];
            float b1 = B1[(ch * 32 + jl) * DIM + m];
            LB[jl * 128 + m] = b0;
            LB[4096 + jl * 128 + m] = b1 - b0;
        }
        __syncthreads();
#pragma unroll 2
        for (int jl = 0; jl < 32; ++jl) {
            int j = ch * 32 + jl;
            float la0[4], la1[4];
#pragma unroll
            for (int i = 0; i < 4; ++i) {
                la0[i] = LA[(kgrp * 4 + i) * 129 + j];
                la1[i] = LA[32 * 129 + (kgrp * 4 + i) * 129 + j];
            }
            f32x4 lb0 = *reinterpret_cast<const f32x4*>(&LB[jl * 128 + mgrp * 4]);
            f32x4 lb1 = *reinterpret_cast<const f32x4*>(&LB[4096 + jl * 128 + mgrp * 4]);
#pragma unroll
            for (int i = 0; i < 4; ++i)
#pragma unroll
                for (int mi = 0; mi < 4; ++mi) {
                    acc[0][0][i][mi] += la0[i] * lb0[mi];
                    acc[1][0][i][mi] += la1[i] * lb0[mi];
                    acc[0][1][i][mi] += la0[i] * lb1[mi];
                    acc[1][1][i][mi] += la1[i] * lb1[mi];
                }
        }
    }

    // write fragments: t = L + 2R
#pragma unroll
    for (int t = 0; t < 4; ++t) {
        int L = t & 1, R = t >> 1;
#pragma unroll
        for (int i = 0; i < 4; ++i)
#pragma unroll
            for (int mi = 0; mi < 4; ++mi) {
                int k = kk * 32 + kgrp * 4 + i;
                int m = mgrp * 4 + mi;
                int g = (k & 31) >> 3, j = k & 7;
                int lane = g * 16 + (m & 15);
                int mm = m >> 4;
                size_t idx =
                    ((((((size_t)p * 4 + t) * 4 + kk) * 8 + mm) * 64 + lane) * 8) + j;
                afrag[idx] = f2h(acc[L][R][i][mi]);
            }
    }
}

// ---------------------------------------------------------------------------
// prep 2: pack occupation bits, one u64 per batch row
// ---------------------------------------------------------------------------
__global__ void prep_bits(const int* __restrict__ onstate,
                          const int* __restrict__ image2,
                          u64* __restrict__ bits) {
    int r = blockIdx.x * blockDim.x + threadIdx.x;
    if (r >= BATCH_N) return;
    const int* row = onstate + (size_t)r * NS;
    u64 b = 0;
#pragma unroll 8
    for (int t = 0; t < NS; ++t) {
        b |= ((u64)(row[image2[t]] & 1)) << t;
    }
    bits[r] = b;
}

// ---------------------------------------------------------------------------
// main: 256 blocks x 512 threads (8 waves); block owns 64 batch rows.
// Wave wid = m-tile (16 dims), all 64 rows. 32 pair-phases (one barrier each).
// Per (kk, rg): 4 masked MFMAs: t0*v + t1*(v.b0) + t2*(v.b1) + t3*(v.b0b1).
// A-term fragments double-buffered in registers across pairs.
// ---------------------------------------------------------------------------
__global__ __launch_bounds__(512, 2)
void mps_pair(const unsigned short* __restrict__ afrag,
              const u64* __restrict__ occbits,
              const float* __restrict__ left,
              const float* __restrict__ right,
              float* __restrict__ out) {
    __shared__ unsigned short vlds[2][64 * DIM];   // 2 x 16 KB, fp16 v, swizzled
    __shared__ float red[64][33];                  // final reduction scratch

    const int tid  = threadIdx.x;
    const int wid  = tid >> 6;          // 0..7 -> m-tile
    const int lane = tid & 63;
    const int li   = lane & 15;
    const int g    = lane >> 4;
    const int rbase = blockIdx.x * 64;

    u64 bits[4];
#pragma unroll
    for (int rg = 0; rg < 4; ++rg)
        bits[rg] = occbits[rbase + rg * 16 + li];

    // hoisted LDS byte offsets (pair-invariant)
    u32 rdoff[4][4];
#pragma unroll
    for (int rg = 0; rg < 4; ++rg)
#pragma unroll
        for (int kk = 0; kk < 4; ++kk) {
            int r = rg * 16 + li;
            rdoff[rg][kk] =
                (u32)(r * 256 + kk * 64 + g * 16) ^ ((u32)(r & 7) << 4);
        }
    u32 wroff[4];
#pragma unroll
    for (int rg = 0; rg < 4; ++rg) {
        int r = rg * 16 + li;
        int mbase = wid * 16 + g * 4;
        wroff[rg] = (u32)(r * 256 + mbase * 2) ^ ((u32)(r & 7) << 4);
    }

    // init v buffer 0 with fp16(left), swizzled
    for (int c = tid; c < 64 * 16; c += 512) {
        int r  = c >> 4;
        int kc = c & 15;
        unsigned short tmp[8];
#pragma unroll
        for (int j = 0; j < 8; ++j) tmp[j] = f2h(left[kc * 8 + j]);
        u32 byte = (u32)(r * 256 + kc * 16) ^ ((u32)(r & 7) << 4);
        *reinterpret_cast<uint4*>(reinterpret_cast<char*>(&vlds[0][0]) + byte) =
            *reinterpret_cast<uint4*>(tmp);
    }
    __syncthreads();

    const f16x8 zf = {0, 0, 0, 0, 0, 0, 0, 0};

    f16x8 ft[2][4][4];   // [buf][term][kk] A-term fragments, double-buffered

#define ISSUE(BUF, P_)                                                        \
    {                                                                         \
        const unsigned short* sb_ = afrag + (size_t)(P_) * 65536;             \
        _Pragma("unroll")                                                     \
        for (int t = 0; t < 4; ++t)                                           \
            _Pragma("unroll")                                                 \
            for (int kk = 0; kk < 4; ++kk)                                    \
                ft[BUF][t][kk] = *reinterpret_cast<const f16x8*>(             \
                    sb_ + ((size_t)((t * 4 + kk) * 8 + wid) * 512) +          \
                    lane * 8);                                                \
    }

#define COMPUTE(P_, BUF)                                                      \
    {                                                                         \
        const int p_ = (P_);                                                  \
        const char* vb = reinterpret_cast<const char*>(&vlds[p_ & 1][0]);     \
        char*       wb = reinterpret_cast<char*>(&vlds[(p_ + 1) & 1][0]);     \
        f32x4 acc[4];                                                         \
        _Pragma("unroll")                                                     \
        for (int rg = 0; rg < 4; ++rg) acc[rg] = (f32x4){0.f, 0.f, 0.f, 0.f}; \
        __builtin_amdgcn_s_setprio(1);                                        \
        _Pragma("unroll")                                                     \
        for (int kk = 0; kk < 4; ++kk) {                                      \
            f16x8 bfr[4];                                                     \
            _Pragma("unroll")                                                 \
            for (int rg = 0; rg < 4; ++rg)                                    \
                bfr[rg] =                                                     \
                    *reinterpret_cast<const f16x8*>(vb + rdoff[rg][kk]);      \
            _Pragma("unroll")                                                 \
            for (int rg = 0; rg < 4; ++rg) {                                  \
                bool m0 = (bits[rg] >> (2 * p_)) & 1;                         \
                bool m1 = (bits[rg] >> (2 * p_ + 1)) & 1;                     \
                f16x8 vb0  = m0 ? bfr[rg] : zf;                               \
                f16x8 vb1  = m1 ? bfr[rg] : zf;                               \
                f16x8 vb01 = m1 ? vb0 : zf;                                   \
                acc[rg] = __builtin_amdgcn_mfma_f32_16x16x32_f16(             \
                    ft[BUF][0][kk], bfr[rg], acc[rg], 0, 0, 0);               \
                acc[rg] = __builtin_amdgcn_mfma_f32_16x16x32_f16(             \
                    ft[BUF][1][kk], vb0, acc[rg], 0, 0, 0);                   \
                acc[rg] = __builtin_amdgcn_mfma_f32_16x16x32_f16(             \
                    ft[BUF][2][kk], vb1, acc[rg], 0, 0, 0);                   \
                acc[rg] = __builtin_amdgcn_mfma_f32_16x16x32_f16(             \
                    ft[BUF][3][kk], vb01, acc[rg], 0, 0, 0);                  \
            }                                                                 \
        }                                                                     \
        __builtin_amdgcn_s_setprio(0);                                        \
        if (p_ < NP - 1) {                                                    \
            _Pragma("unroll")                                                 \
            for (int rg = 0; rg < 4; ++rg) {                                  \
                u32 lo = ((u32)f2h(acc[rg][1]) << 16) | f2h(acc[rg][0]);      \
                u32 hi = ((u32)f2h(acc[rg][3]) << 16) | f2h(acc[rg][2]);      \
                uint2 w = {lo, hi};                                           \
                *reinterpret_cast<uint2*>(wb + wroff[rg]) = w;                \
            }                                                                 \
            __syncthreads();                                                  \
        } else {                                                              \
            int mcol = wid * 16 + g * 4;                                      \
            const float4 rv = *reinterpret_cast<const float4*>(right + mcol); \
            _Pragma("unroll")                                                 \
            for (int rg = 0; rg < 4; ++rg) {                                  \
                float pv = acc[rg][0] * rv.x + acc[rg][1] * rv.y +            \
                           acc[rg][2] * rv.z + acc[rg][3] * rv.w;             \
                red[rg * 16 + li][wid * 4 + g] = pv;                          \
            }                                                                 \
            __syncthreads();                                                  \
            if (tid < 64) {                                                   \
                float ssum = 0.f;                                             \
                _Pragma("unroll")                                             \
                for (int i = 0; i < 32; ++i) ssum += red[tid][i];             \
                out[rbase + tid] = ssum;                                      \
            }                                                                 \
        }                                                                     \
    }

    ISSUE(0, 0);
    for (int pp = 0; pp < NP; pp += 2) {
        ISSUE(1, pp + 1);                          // prefetch odd pair
        COMPUTE(pp, 0);
        if (pp + 2 < NP) ISSUE(0, pp + 2);         // prefetch next even pair
        COMPUTE(pp + 1, 1);
    }

#undef ISSUE
#undef COMPUTE
}

// ---------------------------------------------------------------------------
extern "C" void kernel_launch(void* const* d_in, const int* in_sizes, int n_in,
                              void* d_out, int out_size, void* d_ws, size_t ws_size,
                              hipStream_t stream) {
    const int*   onstate = (const int*)d_in[0];
    const float* data    = (const float*)d_in[1];
    const float* left    = (const float*)d_in[2];
    const float* right   = (const float*)d_in[3];
    const int*   image2  = (const int*)d_in[4];
    float* out = (float*)d_out;

    unsigned short* afrag = (unsigned short*)d_ws;                       // 4 MB
    u64* bits = (u64*)((char*)d_ws + (size_t)2097152 * sizeof(unsigned short));

    prep_pair_frags<<<128, 256, 0, stream>>>(data, afrag);
    prep_bits<<<64, 256, 0, stream>>>(onstate, image2, bits);
    mps_pair<<<256, 512, 0, stream>>>(afrag, bits, left, right, out);
}